// Round 9
// baseline (297.269 us; speedup 1.0000x reference)
//
#include <hip/hip_runtime.h>
#include <hip/hip_bf16.h>

#define N_NODES 8192
#define N_EDGES 262144
#define IN_DIM 256
#define HID 256
#define OUT_DIM 64
#define PATH_DIM 64
#define NHEADS 4
#define DH 16
#define KSPLIT 8
#define SPLIT_KEYS (N_NODES / KSPLIT)   // 1024
#define NITER (SPLIT_KEYS / 64)         // 16 (wave strip: 16 keys/iter, 4 waves interleaved)

typedef __attribute__((ext_vector_type(8))) short bf16x8;
typedef __attribute__((ext_vector_type(4))) short bf16x4;
typedef __attribute__((ext_vector_type(4))) float f32x4;

__device__ __forceinline__ ushort f2bf(float f) {
  union { float f; unsigned int u; } c;
  c.f = f;
  unsigned int u = c.u;
  u += 0x7fffu + ((u >> 16) & 1u);
  return (ushort)(u >> 16);
}

__device__ __forceinline__ float fast_exp2(float x) {
  float r;
  asm("v_exp_f32 %0, %1" : "=v"(r) : "v"(x));
  return r;
}

__device__ __forceinline__ unsigned pack_bf16(float a, float b) {
  union { __hip_bfloat162 h; unsigned u; } c;
  c.h = __float22bfloat162_rn(make_float2(a, b));
  return c.u;
}

// PV matrix op: 16x16x16 bf16 (K=16). Instruction exists on gfx950 (ISA §10).
#if __has_builtin(__builtin_amdgcn_mfma_f32_16x16x16bf16_1k)
__device__ __forceinline__ f32x4 mfma16(bf16x4 a, bf16x4 b, f32x4 c) {
  return __builtin_amdgcn_mfma_f32_16x16x16bf16_1k(a, b, c, 0, 0, 0);
}
#else
__device__ __forceinline__ f32x4 mfma16(bf16x4 a, bf16x4 b, f32x4 c) {
  f32x4 d;
  asm volatile("v_mfma_f32_16x16x16_bf16 %0, %1, %2, %3\n\ts_nop 7\n\ts_nop 3"
               : "=v"(d) : "v"(a), "v"(b), "v"(c));
  return d;
}
#endif

// ---------------- graph setup ----------------

__global__ __launch_bounds__(256) void init_graph(int* deg, int* cursor) {
  int i = blockIdx.x * 256 + threadIdx.x;
  if (i < N_NODES) { deg[i] = 1; cursor[i] = 0; }   // deg starts at 1 (self loop)
}

__global__ __launch_bounds__(256) void count_deg(const int* __restrict__ dst,
                                                 int* __restrict__ deg) {
  int e = blockIdx.x * 256 + threadIdx.x;
  if (e < N_EDGES) atomicAdd(&deg[dst[e]], 1);
}

__global__ __launch_bounds__(256) void scan_rows(const int* __restrict__ deg,
                                                 int* __restrict__ row_off,
                                                 float* __restrict__ dinv) {
  __shared__ int part[256];
  int t = threadIdx.x;
  int base = t * 32;
  int local[32];
  int s = 0;
  #pragma unroll
  for (int i = 0; i < 32; ++i) {
    int c = deg[base + i] - 1;
    local[i] = s;
    s += c;
  }
  part[t] = s;
  __syncthreads();
  for (int d = 1; d < 256; d <<= 1) {
    int v = (t >= d) ? part[t - d] : 0;
    __syncthreads();
    part[t] += v;
    __syncthreads();
  }
  int prev = (t == 0) ? 0 : part[t - 1];
  #pragma unroll
  for (int i = 0; i < 32; ++i) {
    row_off[base + i] = prev + local[i];
    dinv[base + i] = rsqrtf((float)deg[base + i]);
  }
}

__global__ __launch_bounds__(256) void fill_csr(const int* __restrict__ src,
                                                const int* __restrict__ dst,
                                                const int* __restrict__ row_off,
                                                int* __restrict__ cursor,
                                                int* __restrict__ csr) {
  int e = blockIdx.x * 256 + threadIdx.x;
  if (e < N_EDGES) {
    int d = dst[e];
    int p = atomicAdd(&cursor[d], 1);
    csr[row_off[d] + p] = src[e];
  }
}

// ---------------- small utility ----------------

__global__ __launch_bounds__(256) void transpose_w(const float* __restrict__ W,
                                                   float* __restrict__ Wt,
                                                   int R, int C) {
  int i = blockIdx.x * 256 + threadIdx.x;
  if (i < R * C) {
    int r = i / C, c = i % C;
    Wt[c * R + r] = W[i];
  }
}

// qkv f32 [8192][192] -> Qbf [4][8192][32] (x0.25*log2e, upper 16 zero),
//                        Kbf [4][8192][32] (upper 16 zero),
//                        Vtb [4][16][8192]
__global__ __launch_bounds__(256) void convert_qkv(const float* __restrict__ qkv,
                                                   ushort* __restrict__ Qbf,
                                                   ushort* __restrict__ Kbf,
                                                   ushort* __restrict__ Vtb) {
  const int tg = blockIdx.x * 256 + threadIdx.x;  // 0..32767
  const int h = tg >> 13;
  const int n = tg & 8191;
  const float SC = 0.36067376022224085f;  // 0.25 * log2(e)
  const float* base = qkv + (size_t)n * 192 + h * 16;
  ushort* qd = Qbf + ((size_t)h * 8192 + n) * 32;
  ushort* kd = Kbf + ((size_t)h * 8192 + n) * 32;
  ushort4 zz = make_ushort4(0, 0, 0, 0);
  #pragma unroll
  for (int i = 0; i < 16; i += 4) {
    float4 q4 = *reinterpret_cast<const float4*>(base + i);
    float4 k4 = *reinterpret_cast<const float4*>(base + 64 + i);
    float4 v4 = *reinterpret_cast<const float4*>(base + 128 + i);
    *reinterpret_cast<ushort4*>(qd + i) =
        make_ushort4(f2bf(q4.x * SC), f2bf(q4.y * SC), f2bf(q4.z * SC), f2bf(q4.w * SC));
    *reinterpret_cast<ushort4*>(kd + i) =
        make_ushort4(f2bf(k4.x), f2bf(k4.y), f2bf(k4.z), f2bf(k4.w));
    *reinterpret_cast<ushort4*>(qd + 16 + i) = zz;
    *reinterpret_cast<ushort4*>(kd + 16 + i) = zz;
    Vtb[((size_t)h * 16 + i + 0) * 8192 + n] = f2bf(v4.x);
    Vtb[((size_t)h * 16 + i + 1) * 8192 + n] = f2bf(v4.y);
    Vtb[((size_t)h * 16 + i + 2) * 8192 + n] = f2bf(v4.z);
    Vtb[((size_t)h * 16 + i + 3) * 8192 + n] = f2bf(v4.w);
  }
}

// ---------------- fp32 GEMM (64x64 tile) ----------------

template <bool RELU, bool BIAS>
__global__ __launch_bounds__(256) void gemm_tile(const float* __restrict__ A1, int K1,
                                                 const float* __restrict__ A2, int K2,
                                                 const float* __restrict__ B,
                                                 const float* __restrict__ bias,
                                                 float* __restrict__ C, int N) {
  __shared__ __align__(16) float As[16][64];
  __shared__ __align__(16) float Bs[16][68];
  const int K = K1 + K2;
  const int bm = blockIdx.y * 64;
  const int bn = blockIdx.x * 64;
  const int t = threadIdx.x;
  const int tx = t & 15, ty = t >> 4;
  const int am = t >> 2;
  const int ak = (t & 3) << 2;
  const int bk = t >> 4;
  const int bn4 = (t & 15) << 2;
  float acc[4][4] = {};
  for (int k0 = 0; k0 < K; k0 += 16) {
    int kk = k0 + ak;
    int row = bm + am;
    float4 av;
    if (kk < K1)
      av = *reinterpret_cast<const float4*>(A1 + (size_t)row * K1 + kk);
    else
      av = *reinterpret_cast<const float4*>(A2 + (size_t)row * K2 + (kk - K1));
    As[ak + 0][am] = av.x;
    As[ak + 1][am] = av.y;
    As[ak + 2][am] = av.z;
    As[ak + 3][am] = av.w;
    float4 bv = *reinterpret_cast<const float4*>(B + (size_t)(k0 + bk) * N + bn + bn4);
    *reinterpret_cast<float4*>(&Bs[bk][bn4]) = bv;
    __syncthreads();
    #pragma unroll
    for (int k = 0; k < 16; ++k) {
      float4 a = *reinterpret_cast<const float4*>(&As[k][ty << 2]);
      float4 b = *reinterpret_cast<const float4*>(&Bs[k][tx << 2]);
      acc[0][0] += a.x * b.x; acc[0][1] += a.x * b.y; acc[0][2] += a.x * b.z; acc[0][3] += a.x * b.w;
      acc[1][0] += a.y * b.x; acc[1][1] += a.y * b.y; acc[1][2] += a.y * b.z; acc[1][3] += a.y * b.w;
      acc[2][0] += a.z * b.x; acc[2][1] += a.z * b.y; acc[2][2] += a.z * b.z; acc[2][3] += a.z * b.w;
      acc[3][0] += a.w * b.x; acc[3][1] += a.w * b.y; acc[3][2] += a.w * b.z; acc[3][3] += a.w * b.w;
    }
    __syncthreads();
  }
  #pragma unroll
  for (int i = 0; i < 4; ++i) {
    int row = bm + (ty << 2) + i;
    float4 o = make_float4(acc[i][0], acc[i][1], acc[i][2], acc[i][3]);
    if (BIAS) {
      float4 bv = *reinterpret_cast<const float4*>(bias + bn + (tx << 2));
      o.x += bv.x; o.y += bv.y; o.z += bv.z; o.w += bv.w;
    }
    if (RELU) {
      o.x = fmaxf(o.x, 0.f); o.y = fmaxf(o.y, 0.f);
      o.z = fmaxf(o.z, 0.f); o.w = fmaxf(o.w, 0.f);
    }
    *reinterpret_cast<float4*>(C + (size_t)row * N + bn + (tx << 2)) = o;
  }
}

// ---------------- MFMA flash attention v5 (in-register P, barrier-free) ----------------
// grid (128 qblocks, 4 heads, KSPLIT) x 256 threads (4 waves).
// Wave wv handles keys {kz*1024 + c*64 + wv*16 + 0..15}, c = 0..15, for all 64 q.
// QK^T swapped: mfma_16x16x32(A=K, B=Q) -> C[key][q]: lane holds q=lane&15,
// keys lg*4+r -- which is EXACTLY the A-fragment layout of mfma_16x16x16
// (row=lane&15, k=lg*4+j). So P = exp(C) stays in registers; PV B-frag (V^T)
// is a direct 8B global load. Zero LDS / zero barriers in the main loop;
// one epilogue barrier reduces O / denominator partials across the 4 waves.

__global__ __launch_bounds__(256) void attn_mfma5(const ushort* __restrict__ Qbf,
                                                  const ushort* __restrict__ Kbf,
                                                  const ushort* __restrict__ Vtb,
                                                  float* __restrict__ Opart,
                                                  float* __restrict__ Wpart) {
  const int h  = blockIdx.y;
  const int qb = blockIdx.x;
  const int kz = blockIdx.z;
  const int t  = threadIdx.x;
  const int wv = t >> 6;
  const int l  = t & 63;
  const int lg = l >> 4;
  const int lc = l & 15;

  __shared__ float red_o[3][64][17];
  __shared__ float red_w[3][64];

  // Q B-fragments (16x16x32): lane holds Q[q=lc][dh=lg*8..+7] (zeros for lg>=2)
  bf16x8 qf[4];
  {
    const ushort* qbase = Qbf + ((size_t)h * 8192 + qb * 64) * 32;
    #pragma unroll
    for (int qt = 0; qt < 4; ++qt)
      qf[qt] = *reinterpret_cast<const bf16x8*>(qbase + (qt * 16 + lc) * 32 + lg * 8);
  }

  // K A-fragment pointer: row=key=strip+lc, k=dh=lg*8+j
  const ushort* kptr =
      Kbf + ((size_t)h * 8192 + kz * SPLIT_KEYS + wv * 16 + lc) * 32 + lg * 8;
  // V^T B-fragment pointer (16x16x16): B[k=key=strip+lg*4+j][n=dh=lc]
  const ushort* vptr =
      Vtb + ((size_t)h * 16 + lc) * 8192 + kz * SPLIT_KEYS + wv * 16 + lg * 4;

  f32x4 oacc[4] = {{0.f, 0.f, 0.f, 0.f}, {0.f, 0.f, 0.f, 0.f},
                   {0.f, 0.f, 0.f, 0.f}, {0.f, 0.f, 0.f, 0.f}};
  float wsum[4] = {0.f, 0.f, 0.f, 0.f};

  bf16x8 kf = *reinterpret_cast<const bf16x8*>(kptr);
  bf16x4 vf = *reinterpret_cast<const bf16x4*>(vptr);

  for (int c = 0; c < NITER; ++c) {
    bf16x8 kf_n;
    bf16x4 vf_n;
    if (c + 1 < NITER) {
      kf_n = *reinterpret_cast<const bf16x8*>(kptr + (size_t)(c + 1) * 64 * 32);
      vf_n = *reinterpret_cast<const bf16x4*>(vptr + (size_t)(c + 1) * 64);
    }

    // QK^T: C[key(strip)][q] per 16-q tile
    f32x4 s[4];
    #pragma unroll
    for (int qt = 0; qt < 4; ++qt) {
      f32x4 z = {0.f, 0.f, 0.f, 0.f};
      s[qt] = __builtin_amdgcn_mfma_f32_16x16x32_bf16(kf, qf[qt], z, 0, 0, 0);
    }

    // exp2 -> in-register P fragment -> PV (16x16x16, K=16 keys)
    #pragma unroll
    for (int qt = 0; qt < 4; ++qt) {
      float e0 = fast_exp2(s[qt][0]);
      float e1 = fast_exp2(s[qt][1]);
      float e2 = fast_exp2(s[qt][2]);
      float e3 = fast_exp2(s[qt][3]);
      wsum[qt] += (e0 + e1) + (e2 + e3);
      uint2 pk;
      pk.x = pack_bf16(e0, e1);
      pk.y = pack_bf16(e2, e3);
      bf16x4 pf;
      pf[0] = (short)(pk.x & 0xffff); pf[1] = (short)(pk.x >> 16);
      pf[2] = (short)(pk.y & 0xffff); pf[3] = (short)(pk.y >> 16);
      oacc[qt] = mfma16(pf, vf, oacc[qt]);
    }

    kf = kf_n;
    vf = vf_n;
  }

  // ---- denominator: reduce over lg (keys within wave) ----
  #pragma unroll
  for (int qt = 0; qt < 4; ++qt) {
    float v = wsum[qt];
    v += __shfl_xor(v, 16);
    v += __shfl_xor(v, 32);
    wsum[qt] = v;   // strip total for q = qt*16 + lc
  }

  // ---- cross-wave reduce (single barrier) ----
  if (wv > 0) {
    #pragma unroll
    for (int qt = 0; qt < 4; ++qt) {
      #pragma unroll
      for (int r = 0; r < 4; ++r)
        red_o[wv - 1][qt * 16 + lg * 4 + r][lc] = oacc[qt][r];
      if (lg == 0) red_w[wv - 1][qt * 16 + lc] = wsum[qt];
    }
  }
  __syncthreads();

  if (wv == 0) {
    const size_t obase = ((size_t)(kz * NHEADS + h) * N_NODES + qb * 64);
    #pragma unroll
    for (int qt = 0; qt < 4; ++qt) {
      #pragma unroll
      for (int r = 0; r < 4; ++r) {
        const int q = qt * 16 + lg * 4 + r;
        float o = oacc[qt][r] + red_o[0][q][lc] + red_o[1][q][lc] + red_o[2][q][lc];
        Opart[(obase + q) * 16 + lc] = o;
      }
      if (lg == 0) {
        const int q = qt * 16 + lc;
        Wpart[obase + q] = wsum[qt] + red_w[0][q] + red_w[1][q] + red_w[2][q];
      }
    }
  }
}

// combine: attn_out[n][h*16+d] = sum_s Opart[s][h][n][d] / sum_s Wpart[s][h][n]
__global__ __launch_bounds__(256) void attn_combine(const float* __restrict__ Opart,
                                                    const float* __restrict__ Wpart,
                                                    float* __restrict__ attn_out) {
  int i = blockIdx.x * 256 + threadIdx.x;  // 0 .. 4*8192*4-1
  int dq = i & 3;
  int hn = i >> 2;
  int h = hn >> 13;
  int n = hn & 8191;
  float4 acc = make_float4(0.f, 0.f, 0.f, 0.f);
  float ws = 0.f;
  #pragma unroll
  for (int s = 0; s < KSPLIT; ++s) {
    const size_t row = ((size_t)(s * NHEADS + h) * N_NODES + n);
    float4 v = *reinterpret_cast<const float4*>(Opart + row * 16 + dq * 4);
    acc.x += v.x; acc.y += v.y; acc.z += v.z; acc.w += v.w;
    ws += Wpart[row];
  }
  float inv = 1.f / ws;
  float4 o = make_float4(acc.x * inv, acc.y * inv, acc.z * inv, acc.w * inv);
  *reinterpret_cast<float4*>(attn_out + (size_t)n * 64 + h * 16 + dq * 4) = o;
}

// ---------------- GCN aggregation ----------------
// C=256: 2 rows per block, 2 waves per row (even/odd edge split), LDS combine.

template <bool RELU>
__global__ __launch_bounds__(256) void aggregate2(const float* __restrict__ hw,
                                                  const int* __restrict__ csr,
                                                  const int* __restrict__ row_off,
                                                  const int* __restrict__ deg,
                                                  const float* __restrict__ dinv,
                                                  const float* __restrict__ bias,
                                                  float* __restrict__ out) {
  __shared__ __align__(16) float part[2][256];
  const int t = threadIdx.x;
  const int rw = t >> 7;          // row within block (0..1)
  const int wh = (t >> 6) & 1;    // wave half (even/odd edges)
  const int l = t & 63;
  const int r = blockIdx.x * 2 + rw;
  const float dr = dinv[r];
  const int off = row_off[r];
  const int cnt = deg[r] - 1;
  const int c = l << 2;

  float ax, ay, az, aw;
  if (wh == 0) {
    float4 a = *reinterpret_cast<const float4*>(hw + (size_t)r * 256 + c);
    ax = dr * a.x; ay = dr * a.y; az = dr * a.z; aw = dr * a.w;
  } else {
    ax = ay = az = aw = 0.f;
  }
  for (int e = wh; e < cnt; e += 2) {
    int s = csr[off + e];
    float wsc = dinv[s];
    float4 hv = *reinterpret_cast<const float4*>(hw + (size_t)s * 256 + c);
    ax += wsc * hv.x; ay += wsc * hv.y; az += wsc * hv.z; aw += wsc * hv.w;
  }
  if (wh == 1)
    *reinterpret_cast<float4*>(&part[rw][c]) = make_float4(ax, ay, az, aw);
  __syncthreads();
  if (wh == 0) {
    float4 p = *reinterpret_cast<const float4*>(&part[rw][c]);
    float4 bv = *reinterpret_cast<const float4*>(bias + c);
    float4 o;
    o.x = dr * (ax + p.x) + bv.x;
    o.y = dr * (ay + p.y) + bv.y;
    o.z = dr * (az + p.z) + bv.z;
    o.w = dr * (aw + p.w) + bv.w;
    if (RELU) {
      o.x = fmaxf(o.x, 0.f); o.y = fmaxf(o.y, 0.f);
      o.z = fmaxf(o.z, 0.f); o.w = fmaxf(o.w, 0.f);
    }
    *reinterpret_cast<float4*>(out + (size_t)r * 256 + c) = o;
  }
}

// C=64: one wave per row (layer 3, small)
template <bool RELU>
__global__ __launch_bounds__(256) void aggregate64(const float* __restrict__ hw,
                                                   const int* __restrict__ csr,
                                                   const int* __restrict__ row_off,
                                                   const int* __restrict__ deg,
                                                   const float* __restrict__ dinv,
                                                   const float* __restrict__ bias,
                                                   float* __restrict__ out) {
  const int w = threadIdx.x >> 6, l = threadIdx.x & 63;
  const int r = blockIdx.x * 4 + w;
  const float dr = dinv[r];
  const int off = row_off[r];
  const int cnt = deg[r] - 1;
  float a = dr * hw[(size_t)r * 64 + l];
  for (int e = 0; e < cnt; ++e) {
    int s = csr[off + e];
    a += dinv[s] * hw[(size_t)s * 64 + l];
  }
  float o = dr * a + bias[l];
  if (RELU) o = fmaxf(o, 0.f);
  out[(size_t)r * 64 + l] = o;
}

// ---------------- launch ----------------

extern "C" void kernel_launch(void* const* d_in, const int* in_sizes, int n_in,
                              void* d_out, int out_size, void* d_ws, size_t ws_size,
                              hipStream_t stream) {
  const float* x          = (const float*)d_in[0];
  const int*   ei         = (const int*)d_in[1];
  const float* pe_w       = (const float*)d_in[2];
  const float* pe_b       = (const float*)d_in[3];
  const float* in_proj_w  = (const float*)d_in[4];
  const float* in_proj_b  = (const float*)d_in[5];
  const float* out_proj_w = (const float*)d_in[6];
  const float* out_proj_b = (const float*)d_in[7];
  const float* w1         = (const float*)d_in[8];
  const float* b1         = (const float*)d_in[9];
  const float* w2         = (const float*)d_in[10];
  const float* b2         = (const float*)d_in[11];
  const float* w3         = (const float*)d_in[12];
  const float* b3         = (const float*)d_in[13];

  const int* esrc = ei;
  const int* edst = ei + N_EDGES;

  char* ws = (char*)d_ws;
  size_t o = 0;
  auto take = [&](size_t n) {
    char* p = ws + o;
    o += (n + 255) & ~(size_t)255;
    return p;
  };
  float* pf       = (float*)take((size_t)N_NODES * PATH_DIM * 4);
  float* qkv      = (float*)take((size_t)N_NODES * 3 * PATH_DIM * 4);
  float* attn_out = (float*)take((size_t)N_NODES * PATH_DIM * 4);
  float* pa       = (float*)take((size_t)N_NODES * PATH_DIM * 4);
  float* hw       = (float*)take((size_t)N_NODES * HID * 4);   // 8 MB
  float* h1       = (float*)take((size_t)N_NODES * HID * 4);   // 8 MB (right after hw)
  float* h2       = (float*)take((size_t)N_NODES * HID * 4);   // 8 MB
  float* Wt_in    = (float*)take((size_t)3 * PATH_DIM * PATH_DIM * 4);
  float* Wt_out   = (float*)take((size_t)PATH_DIM * PATH_DIM * 4);
  float* dinv     = (float*)take((size_t)N_NODES * 4);
  int*   deg      = (int*)take((size_t)N_NODES * 4);
  int*   cursor   = (int*)take((size_t)N_NODES * 4);
  int*   row_off  = (int*)take((size_t)N_NODES * 4);
  int*   csr      = (int*)take((size_t)N_EDGES * 4);

  // bf16 attention operands alias h2 (dead until layer-2 aggregate): 5 MB <= 8 MB.
  ushort* Qbf = (ushort*)h2;
  ushort* Kbf = Qbf + (size_t)NHEADS * N_NODES * 32;
  ushort* Vtb = Kbf + (size_t)NHEADS * N_NODES * 32;
  // attention partials: Opart spans hw..h1 (16 MB, contiguous, dead during attn);
  // Wpart aliases pa (1 MB of 2 MB).
  float* Opart = hw;   // [KSPLIT][NHEADS][N_NODES][16] f32 = 16 MB
  float* Wpart = pa;   // [KSPLIT][NHEADS][N_NODES]     f32 = 1 MB

  init_graph<<<N_NODES / 256, 256, 0, stream>>>(deg, cursor);
  count_deg<<<N_EDGES / 256, 256, 0, stream>>>(edst, deg);
  scan_rows<<<1, 256, 0, stream>>>(deg, row_off, dinv);
  fill_csr<<<N_EDGES / 256, 256, 0, stream>>>(esrc, edst, row_off, cursor, csr);

  transpose_w<<<(192 * 64 + 255) / 256, 256, 0, stream>>>(in_proj_w, Wt_in, 192, 64);
  transpose_w<<<(64 * 64 + 255) / 256, 256, 0, stream>>>(out_proj_w, Wt_out, 64, 64);

  gemm_tile<false, true><<<dim3(1, 128), 256, 0, stream>>>(x, IN_DIM, nullptr, 0, pe_w, pe_b, pf, PATH_DIM);
  gemm_tile<false, true><<<dim3(3, 128), 256, 0, stream>>>(pf, PATH_DIM, nullptr, 0, Wt_in, in_proj_b, qkv, 3 * PATH_DIM);

  convert_qkv<<<(N_NODES * NHEADS) / 256, 256, 0, stream>>>(qkv, Qbf, Kbf, Vtb);
  attn_mfma5<<<dim3(128, 4, KSPLIT), 256, 0, stream>>>(Qbf, Kbf, Vtb, Opart, Wpart);
  attn_combine<<<(NHEADS * N_NODES * 4) / 256, 256, 0, stream>>>(Opart, Wpart, attn_out);

  gemm_tile<false, true><<<dim3(1, 128), 256, 0, stream>>>(attn_out, PATH_DIM, nullptr, 0, Wt_out, out_proj_b, pa, PATH_DIM);

  gemm_tile<false, false><<<dim3(4, 128), 256, 0, stream>>>(x, IN_DIM, pa, PATH_DIM, w1, nullptr, hw, HID);
  aggregate2<true><<<N_NODES / 2, 256, 0, stream>>>(hw, csr, row_off, deg, dinv, b1, h1);
  gemm_tile<false, false><<<dim3(4, 128), 256, 0, stream>>>(h1, HID, nullptr, 0, w2, nullptr, hw, HID);
  aggregate2<true><<<N_NODES / 2, 256, 0, stream>>>(hw, csr, row_off, deg, dinv, b2, h2);
  gemm_tile<false, false><<<dim3(1, 128), 256, 0, stream>>>(h2, HID, nullptr, 0, w3, nullptr, hw, OUT_DIM);
  aggregate64<false><<<N_NODES / 4, 256, 0, stream>>>(hw, csr, row_off, deg, dinv, b3, (float*)d_out);
}

// Round 10
// 275.137 us; speedup vs baseline: 1.0804x; 1.0804x over previous
//
#include <hip/hip_runtime.h>
#include <hip/hip_bf16.h>

#define N_NODES 8192
#define N_EDGES 262144
#define IN_DIM 256
#define HID 256
#define OUT_DIM 64
#define PATH_DIM 64
#define NHEADS 4
#define DH 16
#define KSPLIT 8
#define SPLIT_KEYS (N_NODES / KSPLIT)   // 1024
#define NITER (SPLIT_KEYS / 64)         // 16

typedef __attribute__((ext_vector_type(8))) short bf16x8;
typedef __attribute__((ext_vector_type(4))) short bf16x4;
typedef __attribute__((ext_vector_type(4))) float f32x4;

__device__ __forceinline__ ushort f2bf(float f) {
  union { float f; unsigned int u; } c;
  c.f = f;
  unsigned int u = c.u;
  u += 0x7fffu + ((u >> 16) & 1u);
  return (ushort)(u >> 16);
}

__device__ __forceinline__ float bf2f(ushort u) {
  union { float f; unsigned int u; } c;
  c.u = ((unsigned int)u) << 16;
  return c.f;
}

__device__ __forceinline__ float fast_exp2(float x) {
  float r;
  asm("v_exp_f32 %0, %1" : "=v"(r) : "v"(x));
  return r;
}

__device__ __forceinline__ unsigned pack_bf16(float a, float b) {
  union { __hip_bfloat162 h; unsigned u; } c;
  c.h = __float22bfloat162_rn(make_float2(a, b));
  return c.u;
}

// PV matrix op: 16x16x16 bf16 (K=16).
#if __has_builtin(__builtin_amdgcn_mfma_f32_16x16x16bf16_1k)
__device__ __forceinline__ f32x4 mfma16(bf16x4 a, bf16x4 b, f32x4 c) {
  return __builtin_amdgcn_mfma_f32_16x16x16bf16_1k(a, b, c, 0, 0, 0);
}
#else
__device__ __forceinline__ f32x4 mfma16(bf16x4 a, bf16x4 b, f32x4 c) {
  f32x4 d;
  asm volatile("v_mfma_f32_16x16x16_bf16 %0, %1, %2, %3\n\ts_nop 7\n\ts_nop 3"
               : "=v"(d) : "v"(a), "v"(b), "v"(c));
  return d;
}
#endif

// ---------------- graph setup ----------------

__global__ __launch_bounds__(256) void init_graph(int* deg, int* cursor) {
  int i = blockIdx.x * 256 + threadIdx.x;
  if (i < N_NODES) { deg[i] = 1; cursor[i] = 0; }   // deg starts at 1 (self loop)
}

__global__ __launch_bounds__(256) void count_deg(const int* __restrict__ dst,
                                                 int* __restrict__ deg) {
  int e = blockIdx.x * 256 + threadIdx.x;
  if (e < N_EDGES) atomicAdd(&deg[dst[e]], 1);
}

__global__ __launch_bounds__(256) void scan_rows(const int* __restrict__ deg,
                                                 int* __restrict__ row_off,
                                                 float* __restrict__ dinv) {
  __shared__ int part[256];
  int t = threadIdx.x;
  int base = t * 32;
  int local[32];
  int s = 0;
  #pragma unroll
  for (int i = 0; i < 32; ++i) {
    int c = deg[base + i] - 1;
    local[i] = s;
    s += c;
  }
  part[t] = s;
  __syncthreads();
  for (int d = 1; d < 256; d <<= 1) {
    int v = (t >= d) ? part[t - d] : 0;
    __syncthreads();
    part[t] += v;
    __syncthreads();
  }
  int prev = (t == 0) ? 0 : part[t - 1];
  #pragma unroll
  for (int i = 0; i < 32; ++i) {
    row_off[base + i] = prev + local[i];
    dinv[base + i] = rsqrtf((float)deg[base + i]);
  }
}

__global__ __launch_bounds__(256) void fill_csr(const int* __restrict__ src,
                                                const int* __restrict__ dst,
                                                const int* __restrict__ row_off,
                                                int* __restrict__ cursor,
                                                int* __restrict__ csr) {
  int e = blockIdx.x * 256 + threadIdx.x;
  if (e < N_EDGES) {
    int d = dst[e];
    int p = atomicAdd(&cursor[d], 1);
    csr[row_off[d] + p] = src[e];
  }
}

// ---------------- small utility ----------------

__global__ __launch_bounds__(256) void transpose_w(const float* __restrict__ W,
                                                   float* __restrict__ Wt,
                                                   int R, int C) {
  int i = blockIdx.x * 256 + threadIdx.x;
  if (i < R * C) {
    int r = i / C, c = i % C;
    Wt[c * R + r] = W[i];
  }
}

// W [K][N] fp32 -> Bt_hi/Bt_lo [N][K] bf16 split (W = hi + lo exactly to ~2^-18)
__global__ __launch_bounds__(256) void convert_wsplit(const float* __restrict__ W,
                                                      ushort* __restrict__ Bthi,
                                                      ushort* __restrict__ Btlo,
                                                      int K, int N) {
  int i = blockIdx.x * 256 + threadIdx.x;
  if (i < K * N) {
    int k = i / N, n = i % N;
    float v = W[i];
    ushort hi = f2bf(v);
    ushort lo = f2bf(v - bf2f(hi));
    Bthi[(size_t)n * K + k] = hi;
    Btlo[(size_t)n * K + k] = lo;
  }
}

// Axpa bf16 [8192][320] = concat(x fp32 [8192][256], pa fp32 [8192][64])
__global__ __launch_bounds__(256) void convert_xpa(const float* __restrict__ x,
                                                   const float* __restrict__ pa,
                                                   ushort* __restrict__ Axpa) {
  int i = blockIdx.x * 256 + threadIdx.x;   // 0 .. 8192*80-1
  int n = i / 80;
  int c = (i % 80) * 4;
  float4 v;
  if (c < 256)
    v = *reinterpret_cast<const float4*>(x + (size_t)n * 256 + c);
  else
    v = *reinterpret_cast<const float4*>(pa + (size_t)n * 64 + (c - 256));
  *reinterpret_cast<ushort4*>(Axpa + (size_t)n * 320 + c) =
      make_ushort4(f2bf(v.x), f2bf(v.y), f2bf(v.z), f2bf(v.w));
}

// qkv f32 [8192][192] -> Qbf [4][8192][32] (x0.25*log2e, upper 16 zero),
//                        Kbf [4][8192][32] (upper 16 zero),
//                        Vtb [4][16][8192]
__global__ __launch_bounds__(256) void convert_qkv(const float* __restrict__ qkv,
                                                   ushort* __restrict__ Qbf,
                                                   ushort* __restrict__ Kbf,
                                                   ushort* __restrict__ Vtb) {
  const int tg = blockIdx.x * 256 + threadIdx.x;  // 0..32767
  const int h = tg >> 13;
  const int n = tg & 8191;
  const float SC = 0.36067376022224085f;  // 0.25 * log2(e)
  const float* base = qkv + (size_t)n * 192 + h * 16;
  ushort* qd = Qbf + ((size_t)h * 8192 + n) * 32;
  ushort* kd = Kbf + ((size_t)h * 8192 + n) * 32;
  ushort4 zz = make_ushort4(0, 0, 0, 0);
  #pragma unroll
  for (int i = 0; i < 16; i += 4) {
    float4 q4 = *reinterpret_cast<const float4*>(base + i);
    float4 k4 = *reinterpret_cast<const float4*>(base + 64 + i);
    float4 v4 = *reinterpret_cast<const float4*>(base + 128 + i);
    *reinterpret_cast<ushort4*>(qd + i) =
        make_ushort4(f2bf(q4.x * SC), f2bf(q4.y * SC), f2bf(q4.z * SC), f2bf(q4.w * SC));
    *reinterpret_cast<ushort4*>(kd + i) =
        make_ushort4(f2bf(k4.x), f2bf(k4.y), f2bf(k4.z), f2bf(k4.w));
    *reinterpret_cast<ushort4*>(qd + 16 + i) = zz;
    *reinterpret_cast<ushort4*>(kd + 16 + i) = zz;
    Vtb[((size_t)h * 16 + i + 0) * 8192 + n] = f2bf(v4.x);
    Vtb[((size_t)h * 16 + i + 1) * 8192 + n] = f2bf(v4.y);
    Vtb[((size_t)h * 16 + i + 2) * 8192 + n] = f2bf(v4.z);
    Vtb[((size_t)h * 16 + i + 3) * 8192 + n] = f2bf(v4.w);
  }
}

// ---------------- fp32 GEMM (64x64 tile) — attention-side small GEMMs ----------------

template <bool RELU, bool BIAS>
__global__ __launch_bounds__(256) void gemm_tile(const float* __restrict__ A1, int K1,
                                                 const float* __restrict__ A2, int K2,
                                                 const float* __restrict__ B,
                                                 const float* __restrict__ bias,
                                                 float* __restrict__ C, int N) {
  __shared__ __align__(16) float As[16][64];
  __shared__ __align__(16) float Bs[16][68];
  const int K = K1 + K2;
  const int bm = blockIdx.y * 64;
  const int bn = blockIdx.x * 64;
  const int t = threadIdx.x;
  const int tx = t & 15, ty = t >> 4;
  const int am = t >> 2;
  const int ak = (t & 3) << 2;
  const int bk = t >> 4;
  const int bn4 = (t & 15) << 2;
  float acc[4][4] = {};
  for (int k0 = 0; k0 < K; k0 += 16) {
    int kk = k0 + ak;
    int row = bm + am;
    float4 av;
    if (kk < K1)
      av = *reinterpret_cast<const float4*>(A1 + (size_t)row * K1 + kk);
    else
      av = *reinterpret_cast<const float4*>(A2 + (size_t)row * K2 + (kk - K1));
    As[ak + 0][am] = av.x;
    As[ak + 1][am] = av.y;
    As[ak + 2][am] = av.z;
    As[ak + 3][am] = av.w;
    float4 bv = *reinterpret_cast<const float4*>(B + (size_t)(k0 + bk) * N + bn + bn4);
    *reinterpret_cast<float4*>(&Bs[bk][bn4]) = bv;
    __syncthreads();
    #pragma unroll
    for (int k = 0; k < 16; ++k) {
      float4 a = *reinterpret_cast<const float4*>(&As[k][ty << 2]);
      float4 b = *reinterpret_cast<const float4*>(&Bs[k][tx << 2]);
      acc[0][0] += a.x * b.x; acc[0][1] += a.x * b.y; acc[0][2] += a.x * b.z; acc[0][3] += a.x * b.w;
      acc[1][0] += a.y * b.x; acc[1][1] += a.y * b.y; acc[1][2] += a.y * b.z; acc[1][3] += a.y * b.w;
      acc[2][0] += a.z * b.x; acc[2][1] += a.z * b.y; acc[2][2] += a.z * b.z; acc[2][3] += a.z * b.w;
      acc[3][0] += a.w * b.x; acc[3][1] += a.w * b.y; acc[3][2] += a.w * b.z; acc[3][3] += a.w * b.w;
    }
    __syncthreads();
  }
  #pragma unroll
  for (int i = 0; i < 4; ++i) {
    int row = bm + (ty << 2) + i;
    float4 o = make_float4(acc[i][0], acc[i][1], acc[i][2], acc[i][3]);
    if (BIAS) {
      float4 bv = *reinterpret_cast<const float4*>(bias + bn + (tx << 2));
      o.x += bv.x; o.y += bv.y; o.z += bv.z; o.w += bv.w;
    }
    if (RELU) {
      o.x = fmaxf(o.x, 0.f); o.y = fmaxf(o.y, 0.f);
      o.z = fmaxf(o.z, 0.f); o.w = fmaxf(o.w, 0.f);
    }
    *reinterpret_cast<float4*>(C + (size_t)row * N + bn + (tx << 2)) = o;
  }
}

// ---------------- bf16 MFMA GEMM for GCN layers ----------------
// C[M x NT] = A_bf[M x K] @ (Bt_hi + Bt_lo)^T, fp32 accum, bf16 out.
// grid (NT/64, M/64) x 256 threads (4 waves); wave wv owns cols bn+wv*16..+15.
// Fragment layouts identical to attention's verified mfma_16x16x32 usage.

template <int K, int NT>
__global__ __launch_bounds__(256) void gemm_mfma(const ushort* __restrict__ A,
                                                 const ushort* __restrict__ Bthi,
                                                 const ushort* __restrict__ Btlo,
                                                 ushort* __restrict__ C) {
  const int t = threadIdx.x;
  const int wv = t >> 6;
  const int l = t & 63;
  const int lg = l >> 4;
  const int lc = l & 15;
  const int bm = blockIdx.y * 64;
  const int n = blockIdx.x * 64 + wv * 16 + lc;

  const ushort* ap = A + (size_t)(bm + lc) * K + lg * 8;
  const ushort* bh = Bthi + (size_t)n * K + lg * 8;
  const ushort* bl = Btlo + (size_t)n * K + lg * 8;

  f32x4 acc[4] = {{0.f,0.f,0.f,0.f},{0.f,0.f,0.f,0.f},{0.f,0.f,0.f,0.f},{0.f,0.f,0.f,0.f}};
  #pragma unroll 2
  for (int k0 = 0; k0 < K; k0 += 32) {
    bf16x8 vh = *reinterpret_cast<const bf16x8*>(bh + k0);
    bf16x8 vl = *reinterpret_cast<const bf16x8*>(bl + k0);
    #pragma unroll
    for (int mt = 0; mt < 4; ++mt) {
      bf16x8 af = *reinterpret_cast<const bf16x8*>(ap + (size_t)mt * 16 * K + k0);
      acc[mt] = __builtin_amdgcn_mfma_f32_16x16x32_bf16(af, vh, acc[mt], 0, 0, 0);
      acc[mt] = __builtin_amdgcn_mfma_f32_16x16x32_bf16(af, vl, acc[mt], 0, 0, 0);
    }
  }
  #pragma unroll
  for (int mt = 0; mt < 4; ++mt) {
    #pragma unroll
    for (int r = 0; r < 4; ++r)
      C[(size_t)(bm + mt * 16 + lg * 4 + r) * NT + n] = f2bf(acc[mt][r]);
  }
}

// ---------------- MFMA flash attention v5.1 (in-register P, pf reinterpret) ----------------

__global__ __launch_bounds__(256) void attn_mfma5(const ushort* __restrict__ Qbf,
                                                  const ushort* __restrict__ Kbf,
                                                  const ushort* __restrict__ Vtb,
                                                  float* __restrict__ Opart,
                                                  float* __restrict__ Wpart) {
  const int h  = blockIdx.y;
  const int qb = blockIdx.x;
  const int kz = blockIdx.z;
  const int t  = threadIdx.x;
  const int wv = t >> 6;
  const int l  = t & 63;
  const int lg = l >> 4;
  const int lc = l & 15;

  __shared__ float red_o[3][64][17];
  __shared__ float red_w[3][64];

  bf16x8 qf[4];
  {
    const ushort* qbase = Qbf + ((size_t)h * 8192 + qb * 64) * 32;
    #pragma unroll
    for (int qt = 0; qt < 4; ++qt)
      qf[qt] = *reinterpret_cast<const bf16x8*>(qbase + (qt * 16 + lc) * 32 + lg * 8);
  }

  const ushort* kptr =
      Kbf + ((size_t)h * 8192 + kz * SPLIT_KEYS + wv * 16 + lc) * 32 + lg * 8;
  const ushort* vptr =
      Vtb + ((size_t)h * 16 + lc) * 8192 + kz * SPLIT_KEYS + wv * 16 + lg * 4;

  f32x4 oacc[4] = {{0.f, 0.f, 0.f, 0.f}, {0.f, 0.f, 0.f, 0.f},
                   {0.f, 0.f, 0.f, 0.f}, {0.f, 0.f, 0.f, 0.f}};
  float wsum[4] = {0.f, 0.f, 0.f, 0.f};

  bf16x8 kf = *reinterpret_cast<const bf16x8*>(kptr);
  bf16x4 vf = *reinterpret_cast<const bf16x4*>(vptr);

  for (int c = 0; c < NITER; ++c) {
    bf16x8 kf_n;
    bf16x4 vf_n;
    if (c + 1 < NITER) {
      kf_n = *reinterpret_cast<const bf16x8*>(kptr + (size_t)(c + 1) * 64 * 32);
      vf_n = *reinterpret_cast<const bf16x4*>(vptr + (size_t)(c + 1) * 64);
    }

    f32x4 s[4];
    #pragma unroll
    for (int qt = 0; qt < 4; ++qt) {
      f32x4 z = {0.f, 0.f, 0.f, 0.f};
      s[qt] = __builtin_amdgcn_mfma_f32_16x16x32_bf16(kf, qf[qt], z, 0, 0, 0);
    }

    #pragma unroll
    for (int qt = 0; qt < 4; ++qt) {
      float e0 = fast_exp2(s[qt][0]);
      float e1 = fast_exp2(s[qt][1]);
      float e2 = fast_exp2(s[qt][2]);
      float e3 = fast_exp2(s[qt][3]);
      wsum[qt] += (e0 + e1) + (e2 + e3);
      union { uint2 u; bf16x4 v; } pu;
      pu.u.x = pack_bf16(e0, e1);
      pu.u.y = pack_bf16(e2, e3);
      oacc[qt] = mfma16(pu.v, vf, oacc[qt]);
    }

    kf = kf_n;
    vf = vf_n;
  }

  #pragma unroll
  for (int qt = 0; qt < 4; ++qt) {
    float v = wsum[qt];
    v += __shfl_xor(v, 16);
    v += __shfl_xor(v, 32);
    wsum[qt] = v;
  }

  if (wv > 0) {
    #pragma unroll
    for (int qt = 0; qt < 4; ++qt) {
      #pragma unroll
      for (int r = 0; r < 4; ++r)
        red_o[wv - 1][qt * 16 + lg * 4 + r][lc] = oacc[qt][r];
      if (lg == 0) red_w[wv - 1][qt * 16 + lc] = wsum[qt];
    }
  }
  __syncthreads();

  if (wv == 0) {
    const size_t obase = ((size_t)(kz * NHEADS + h) * N_NODES + qb * 64);
    #pragma unroll
    for (int qt = 0; qt < 4; ++qt) {
      #pragma unroll
      for (int r = 0; r < 4; ++r) {
        const int q = qt * 16 + lg * 4 + r;
        float o = oacc[qt][r] + red_o[0][q][lc] + red_o[1][q][lc] + red_o[2][q][lc];
        Opart[(obase + q) * 16 + lc] = o;
      }
      if (lg == 0) {
        const int q = qt * 16 + lc;
        Wpart[obase + q] = wsum[qt] + red_w[0][q] + red_w[1][q] + red_w[2][q];
      }
    }
  }
}

__global__ __launch_bounds__(256) void attn_combine(const float* __restrict__ Opart,
                                                    const float* __restrict__ Wpart,
                                                    float* __restrict__ attn_out) {
  int i = blockIdx.x * 256 + threadIdx.x;
  int dq = i & 3;
  int hn = i >> 2;
  int h = hn >> 13;
  int n = hn & 8191;
  float4 acc = make_float4(0.f, 0.f, 0.f, 0.f);
  float ws = 0.f;
  #pragma unroll
  for (int s = 0; s < KSPLIT; ++s) {
    const size_t row = ((size_t)(s * NHEADS + h) * N_NODES + n);
    float4 v = *reinterpret_cast<const float4*>(Opart + row * 16 + dq * 4);
    acc.x += v.x; acc.y += v.y; acc.z += v.z; acc.w += v.w;
    ws += Wpart[row];
  }
  float inv = 1.f / ws;
  float4 o = make_float4(acc.x * inv, acc.y * inv, acc.z * inv, acc.w * inv);
  *reinterpret_cast<float4*>(attn_out + (size_t)n * 64 + h * 16 + dq * 4) = o;
}

// ---------------- GCN aggregation (bf16 gather, fp32 accum) ----------------
// 256 cols: 2 rows/block, 2 waves/row (even/odd edges), LDS combine.

template <bool RELU, bool OUTBF>
__global__ __launch_bounds__(256) void aggregate_bf(const ushort* __restrict__ hwb,
                                                    const int* __restrict__ csr,
                                                    const int* __restrict__ row_off,
                                                    const int* __restrict__ deg,
                                                    const float* __restrict__ dinv,
                                                    const float* __restrict__ bias,
                                                    ushort* __restrict__ outb,
                                                    float* __restrict__ outf) {
  __shared__ __align__(16) float part[2][256];
  const int t = threadIdx.x;
  const int rw = t >> 7;
  const int wh = (t >> 6) & 1;
  const int l = t & 63;
  const int r = blockIdx.x * 2 + rw;
  const float dr = dinv[r];
  const int off = row_off[r];
  const int cnt = deg[r] - 1;
  const int c = l << 2;

  float a0, a1, a2, a3;
  if (wh == 0) {
    ushort4 u = *reinterpret_cast<const ushort4*>(hwb + (size_t)r * 256 + c);
    a0 = dr * bf2f(u.x); a1 = dr * bf2f(u.y); a2 = dr * bf2f(u.z); a3 = dr * bf2f(u.w);
  } else {
    a0 = a1 = a2 = a3 = 0.f;
  }
  for (int e = wh; e < cnt; e += 2) {
    int s = csr[off + e];
    float wsc = dinv[s];
    ushort4 u = *reinterpret_cast<const ushort4*>(hwb + (size_t)s * 256 + c);
    a0 += wsc * bf2f(u.x); a1 += wsc * bf2f(u.y);
    a2 += wsc * bf2f(u.z); a3 += wsc * bf2f(u.w);
  }
  if (wh == 1)
    *reinterpret_cast<float4*>(&part[rw][c]) = make_float4(a0, a1, a2, a3);
  __syncthreads();
  if (wh == 0) {
    float4 p = *reinterpret_cast<const float4*>(&part[rw][c]);
    float4 bv = *reinterpret_cast<const float4*>(bias + c);
    float o0 = dr * (a0 + p.x) + bv.x;
    float o1 = dr * (a1 + p.y) + bv.y;
    float o2 = dr * (a2 + p.z) + bv.z;
    float o3 = dr * (a3 + p.w) + bv.w;
    if (RELU) {
      o0 = fmaxf(o0, 0.f); o1 = fmaxf(o1, 0.f);
      o2 = fmaxf(o2, 0.f); o3 = fmaxf(o3, 0.f);
    }
    if (OUTBF) {
      *reinterpret_cast<ushort4*>(outb + (size_t)r * 256 + c) =
          make_ushort4(f2bf(o0), f2bf(o1), f2bf(o2), f2bf(o3));
    } else {
      *reinterpret_cast<float4*>(outf + (size_t)r * 256 + c) =
          make_float4(o0, o1, o2, o3);
    }
  }
}

// 64 cols final layer: one wave per row, fp32 output (d_out)
__global__ __launch_bounds__(256) void aggregate64_bf(const ushort* __restrict__ hwb,
                                                      const int* __restrict__ csr,
                                                      const int* __restrict__ row_off,
                                                      const int* __restrict__ deg,
                                                      const float* __restrict__ dinv,
                                                      const float* __restrict__ bias,
                                                      float* __restrict__ out) {
  const int w = threadIdx.x >> 6, l = threadIdx.x & 63;
  const int r = blockIdx.x * 4 + w;
  const float dr = dinv[r];
  const int off = row_off[r];
  const int cnt = deg[r] - 1;
  float a = dr * bf2f(hwb[(size_t)r * 64 + l]);
  for (int e = 0; e < cnt; ++e) {
    int s = csr[off + e];
    a += dinv[s] * bf2f(hwb[(size_t)s * 64 + l]);
  }
  out[(size_t)r * 64 + l] = dr * a + bias[l];
}

// ---------------- launch ----------------

extern "C" void kernel_launch(void* const* d_in, const int* in_sizes, int n_in,
                              void* d_out, int out_size, void* d_ws, size_t ws_size,
                              hipStream_t stream) {
  const float* x          = (const float*)d_in[0];
  const int*   ei         = (const int*)d_in[1];
  const float* pe_w       = (const float*)d_in[2];
  const float* pe_b       = (const float*)d_in[3];
  const float* in_proj_w  = (const float*)d_in[4];
  const float* in_proj_b  = (const float*)d_in[5];
  const float* out_proj_w = (const float*)d_in[6];
  const float* out_proj_b = (const float*)d_in[7];
  const float* w1         = (const float*)d_in[8];
  const float* b1         = (const float*)d_in[9];
  const float* w2         = (const float*)d_in[10];
  const float* b2         = (const float*)d_in[11];
  const float* w3         = (const float*)d_in[12];
  const float* b3         = (const float*)d_in[13];

  const int* esrc = ei;
  const int* edst = ei + N_EDGES;

  char* ws = (char*)d_ws;
  size_t o = 0;
  auto take = [&](size_t n) {
    char* p = ws + o;
    o += (n + 255) & ~(size_t)255;
    return p;
  };
  float* pf       = (float*)take((size_t)N_NODES * PATH_DIM * 4);        // 2 MB
  float* qkv      = (float*)take((size_t)N_NODES * 3 * PATH_DIM * 4);    // 6 MB
  float* attn_out = (float*)take((size_t)N_NODES * PATH_DIM * 4);        // 2 MB
  float* pa       = (float*)take((size_t)N_NODES * PATH_DIM * 4);        // 2 MB
  char*  region1  = take(18874368);                                       // 18 MB shared
  ushort* Qbf     = (ushort*)take((size_t)NHEADS * N_NODES * 32 * 2);    // 2 MB
  ushort* Kbf     = (ushort*)take((size_t)NHEADS * N_NODES * 32 * 2);    // 2 MB
  ushort* Vtb     = (ushort*)take((size_t)NHEADS * DH * N_NODES * 2);    // 1 MB
  ushort* Bt1hi   = (ushort*)take((size_t)HID * 320 * 2);
  ushort* Bt1lo   = (ushort*)take((size_t)HID * 320 * 2);
  ushort* Bt2hi   = (ushort*)take((size_t)HID * HID * 2);
  ushort* Bt2lo   = (ushort*)take((size_t)HID * HID * 2);
  ushort* Bt3hi   = (ushort*)take((size_t)OUT_DIM * HID * 2);
  ushort* Bt3lo   = (ushort*)take((size_t)OUT_DIM * HID * 2);
  float* Wt_in    = (float*)take((size_t)3 * PATH_DIM * PATH_DIM * 4);
  float* Wt_out   = (float*)take((size_t)PATH_DIM * PATH_DIM * 4);
  float* dinv     = (float*)take((size_t)N_NODES * 4);
  int*   deg      = (int*)take((size_t)N_NODES * 4);
  int*   cursor   = (int*)take((size_t)N_NODES * 4);
  int*   row_off  = (int*)take((size_t)N_NODES * 4);
  int*   csr      = (int*)take((size_t)N_EDGES * 4);

  // region1 phase A (attention): Opart 16 MB + Wpart 1 MB
  float* Opart = (float*)region1;
  float* Wpart = (float*)(region1 + 16777216);
  // region1 phase B (GCN trunk, after attn_combine):
  ushort* Axpa  = (ushort*)region1;                  // [8192][320]  5 MB
  ushort* hwbf  = Axpa + (size_t)N_NODES * 320;      // [8192][256]  4 MB
  ushort* h1bf  = hwbf + (size_t)N_NODES * 256;      // [8192][256]  4 MB
  ushort* h2bf  = h1bf + (size_t)N_NODES * 256;      // [8192][256]  4 MB
  ushort* hw64  = h2bf + (size_t)N_NODES * 256;      // [8192][64]   1 MB

  // graph preprocessing
  init_graph<<<N_NODES / 256, 256, 0, stream>>>(deg, cursor);
  count_deg<<<N_EDGES / 256, 256, 0, stream>>>(edst, deg);
  scan_rows<<<1, 256, 0, stream>>>(deg, row_off, dinv);
  fill_csr<<<N_EDGES / 256, 256, 0, stream>>>(esrc, edst, row_off, cursor, csr);

  // weight prep
  transpose_w<<<(192 * 64 + 255) / 256, 256, 0, stream>>>(in_proj_w, Wt_in, 192, 64);
  transpose_w<<<(64 * 64 + 255) / 256, 256, 0, stream>>>(out_proj_w, Wt_out, 64, 64);
  convert_wsplit<<<(320 * 256 + 255) / 256, 256, 0, stream>>>(w1, Bt1hi, Bt1lo, 320, HID);
  convert_wsplit<<<(256 * 256 + 255) / 256, 256, 0, stream>>>(w2, Bt2hi, Bt2lo, HID, HID);
  convert_wsplit<<<(256 * 64 + 255) / 256, 256, 0, stream>>>(w3, Bt3hi, Bt3lo, HID, OUT_DIM);

  // attention path
  gemm_tile<false, true><<<dim3(1, 128), 256, 0, stream>>>(x, IN_DIM, nullptr, 0, pe_w, pe_b, pf, PATH_DIM);
  gemm_tile<false, true><<<dim3(3, 128), 256, 0, stream>>>(pf, PATH_DIM, nullptr, 0, Wt_in, in_proj_b, qkv, 3 * PATH_DIM);
  convert_qkv<<<(N_NODES * NHEADS) / 256, 256, 0, stream>>>(qkv, Qbf, Kbf, Vtb);
  attn_mfma5<<<dim3(128, 4, KSPLIT), 256, 0, stream>>>(Qbf, Kbf, Vtb, Opart, Wpart);
  attn_combine<<<(NHEADS * N_NODES * 4) / 256, 256, 0, stream>>>(Opart, Wpart, attn_out);
  gemm_tile<false, true><<<dim3(1, 128), 256, 0, stream>>>(attn_out, PATH_DIM, nullptr, 0, Wt_out, out_proj_b, pa, PATH_DIM);

  // GCN trunk (bf16 storage, fp32 accumulation)
  convert_xpa<<<(N_NODES * 80) / 256, 256, 0, stream>>>(x, pa, Axpa);
  gemm_mfma<320, 256><<<dim3(4, 128), 256, 0, stream>>>(Axpa, Bt1hi, Bt1lo, hwbf);
  aggregate_bf<true, true><<<N_NODES / 2, 256, 0, stream>>>(hwbf, csr, row_off, deg, dinv, b1, h1bf, nullptr);
  gemm_mfma<256, 256><<<dim3(4, 128), 256, 0, stream>>>(h1bf, Bt2hi, Bt2lo, hwbf);
  aggregate_bf<true, true><<<N_NODES / 2, 256, 0, stream>>>(hwbf, csr, row_off, deg, dinv, b2, h2bf, nullptr);
  gemm_mfma<256, 64><<<dim3(1, 128), 256, 0, stream>>>(h2bf, Bt3hi, Bt3lo, hw64);
  aggregate64_bf<<<N_NODES / 4, 256, 0, stream>>>(hw64, csr, row_off, deg, dinv, b3, (float*)d_out);
}